// Round 6
// baseline (456.029 us; speedup 1.0000x reference)
//
#include <hip/hip_runtime.h>
#include <math.h>

typedef __attribute__((ext_vector_type(8))) short short8;
typedef __attribute__((ext_vector_type(4))) float floatx4;
typedef __attribute__((ext_vector_type(4))) unsigned int uintx4;
typedef __attribute__((ext_vector_type(2))) unsigned int uintx2;

#define MFMA16(a, b, c) __builtin_amdgcn_mfma_f32_16x16x32_bf16((a), (b), (c), 0, 0, 0)

// log2(e) * (1/sqrt(64)) — folded into Q so attention works in exp2 domain
#define QSCALE 0.18033688011112042f

__device__ __forceinline__ unsigned short f2bf(float x) {
    unsigned int u = __float_as_uint(x);
    u += 0x7fffu + ((u >> 16) & 1u);   // round-to-nearest-even
    return (unsigned short)(u >> 16);
}

__device__ __forceinline__ short8 lds8(const unsigned short* p) {
    return *reinterpret_cast<const short8*>(p);
}

// async global->LDS, 16B per lane; LDS dest = wave-uniform base + lane*16
__device__ __forceinline__ void g2l16(const unsigned short* g, unsigned short* l) {
    __builtin_amdgcn_global_load_lds(
        (const __attribute__((address_space(1))) unsigned int*)g,
        (__attribute__((address_space(3))) unsigned int*)l,
        16, 0, 0);
}

// pack two f32 -> bf16x2 dword (RNE): low = a, high = b
__device__ __forceinline__ unsigned int cvtpk(float a, float b) {
    unsigned int r;
    asm("v_cvt_pk_bf16_f32 %0, %1, %2" : "=v"(r) : "v"(a), "v"(b));
    return r;
}

// swap lanes[32:63] of a with lanes[0:31] of b (both modified)
__device__ __forceinline__ void pl32swap(unsigned int& a, unsigned int& b) {
    asm("v_permlane32_swap_b32 %0, %1" : "+v"(a), "+v"(b));
}

// swap odd 16-lane groups of a with even 16-lane groups of b (both modified)
__device__ __forceinline__ void pl16swap(unsigned int& a, unsigned int& b) {
    asm("v_permlane16_swap_b32 %0, %1" : "+v"(a), "+v"(b));
}

// ---------------- prep: fp32 -> bf16 convert (vectorized) ----------------
__global__ void cvt_bf16(const float* __restrict__ src, unsigned short* __restrict__ dst, int n4) {
    int i = blockIdx.x * blockDim.x + threadIdx.x;
    if (i >= n4) return;
    float4 v = reinterpret_cast<const float4*>(src)[i];
    ushort4 o;
    o.x = f2bf(v.x); o.y = f2bf(v.y); o.z = f2bf(v.z); o.w = f2bf(v.w);
    reinterpret_cast<ushort4*>(dst)[i] = o;
}

// ---------------- prep: K window convert (coalesced both sides) ----------------
__global__ void prep_k(const float* __restrict__ kc, unsigned short* __restrict__ Kw) {
    int i = blockIdx.x * blockDim.x + threadIdx.x;   // 0 .. 262143
    int d4  = (i & 15) * 4;
    int s   = (i >> 4) & 1023;
    int bkv = i >> 14;
    size_t src = ((size_t)bkv * 4096 + 3072 + s) * 64 + d4;
    float4 kv = *reinterpret_cast<const float4*>(kc + src);
    ushort4 ko;
    ko.x = f2bf(kv.x); ko.y = f2bf(kv.y); ko.z = f2bf(kv.z); ko.w = f2bf(kv.w);
    *reinterpret_cast<ushort4*>(Kw + ((size_t)bkv * 1024 + s) * 64 + d4) = ko;
}

// ---------------- prep: V window transpose via LDS tile ----------------
__global__ void prep_v(const float* __restrict__ vc, unsigned short* __restrict__ Vt) {
    __shared__ unsigned short tl[64][72];
    const int bkv = blockIdx.x >> 4;
    const int s0  = (blockIdx.x & 15) * 64;
    const int t   = threadIdx.x;
    const int sl  = t >> 2;
    const int dq  = (t & 3) * 16;
    const float* src = vc + ((size_t)bkv * 4096 + 3072 + s0 + sl) * 64 + dq;
    float4 v0 = reinterpret_cast<const float4*>(src)[0];
    float4 v1 = reinterpret_cast<const float4*>(src)[1];
    float4 v2 = reinterpret_cast<const float4*>(src)[2];
    float4 v3 = reinterpret_cast<const float4*>(src)[3];
    tl[dq +  0][sl] = f2bf(v0.x); tl[dq +  1][sl] = f2bf(v0.y);
    tl[dq +  2][sl] = f2bf(v0.z); tl[dq +  3][sl] = f2bf(v0.w);
    tl[dq +  4][sl] = f2bf(v1.x); tl[dq +  5][sl] = f2bf(v1.y);
    tl[dq +  6][sl] = f2bf(v1.z); tl[dq +  7][sl] = f2bf(v1.w);
    tl[dq +  8][sl] = f2bf(v2.x); tl[dq +  9][sl] = f2bf(v2.y);
    tl[dq + 10][sl] = f2bf(v2.z); tl[dq + 11][sl] = f2bf(v2.w);
    tl[dq + 12][sl] = f2bf(v3.x); tl[dq + 13][sl] = f2bf(v3.y);
    tl[dq + 14][sl] = f2bf(v3.z); tl[dq + 15][sl] = f2bf(v3.w);
    __syncthreads();
    const int dl = t >> 2;
    const int sc = (t & 3) * 16;
    unsigned short* dst = Vt + ((size_t)bkv * 64 + dl) * 1024 + s0 + sc;
    short8 x0 = *reinterpret_cast<const short8*>(&tl[dl][sc]);
    short8 x1 = *reinterpret_cast<const short8*>(&tl[dl][sc + 8]);
    *reinterpret_cast<short8*>(dst)     = x0;
    *reinterpret_cast<short8*>(dst + 8) = x1;
}

// ---------------- bf16 MFMA GEMM, 256x256 tile, fine-phased (T3+T4+T5) ----------------
// BK=32 K-tiles; LDS = 2 dbuf x 2 half-slots per matrix (A: 4x8KB, B: 4x8KB,
// 64 KiB total, fragment-order units -> conflict-free ds_read/g2l16 pair).
// Per K-tile: 2 phases, each {ds_read subtile || issue 1 half-tile stage (2x
// g2l16) -> barrier -> setprio -> 16 MFMA -> setprio -> barrier}; vmcnt(2)
// once per K-tile (counted, never 0 mid-loop). Stage schedule (rigorous):
//   P0 of kt stages B(kt+1) (its slot dead since kt-1);
//   P1 of kt stages A(kt+2) (A[d] fully consumed into regs at P0);
//   P1-end vmcnt(2) retires {A(kt+1), B(kt+1)} before kt+1 reads them.
template <int EPI>
__global__ __launch_bounds__(512, 2)
void gemm8p(const unsigned short* __restrict__ A,
            const unsigned short* __restrict__ Bt,
            float* __restrict__ Cf,
            unsigned short* __restrict__ Cb) {
    constexpr int K   = 2048;
    constexpr int NKT = 64;                         // K-tiles of 32
    __shared__ __align__(16) unsigned short sm[32768];   // 64 KiB

    const int tid  = threadIdx.x;
    const int lane = tid & 63;
    const int l15  = lane & 15;
    const int quad = lane >> 4;
    const int wid  = tid >> 6;                      // 0..7
    const int wr   = wid >> 2;                      // M half
    const int wc   = wid & 3;                       // N quarter

    const int bn = blockIdx.x & 7;                  // XCD-friendly B-panel mapping
    const int bm = blockIdx.x >> 3;

    // staging sources (wave w stages row-subtile s=w of each half-tile)
    const unsigned short* gA = A  + (size_t)(bm * 256 + wid * 16 + l15) * K + quad * 8;
    const unsigned short* gB = Bt + (size_t)(bn * 256 + wid * 16 + l15) * K + quad * 8;

#define STA(kt, h) g2l16(gA + (size_t)(h) * 128 * K + (kt) * 32, \
                         sm + (((kt) & 1) * 2 + (h)) * 4096 + wid * 512)
#define STB(kt, h) g2l16(gB + (size_t)(h) * 128 * K + (kt) * 32, \
                         sm + 16384 + (((kt) & 1) * 2 + (h)) * 4096 + wid * 512)

    floatx4 acc[8][4];
#pragma unroll
    for (int i = 0; i < 8; ++i)
#pragma unroll
        for (int j = 0; j < 4; ++j) acc[i][j] = floatx4{0, 0, 0, 0};

    // prologue: stage A(0), B(0), A(1); wait all but A(1)
    STA(0, 0); STA(0, 1); STB(0, 0); STB(0, 1); STA(1, 0); STA(1, 1);
    asm volatile("s_waitcnt vmcnt(2)" ::: "memory");
    __builtin_amdgcn_s_barrier();
    asm volatile("" ::: "memory");

    for (int kt = 0; kt < NKT; ++kt) {
        const int d = kt & 1;
        const unsigned short* As = sm + (d * 2 + wr) * 4096;
        const unsigned short* Bs = sm + 16384 + (d * 2 + (wc >> 1)) * 4096;

        // ---------------- P0: af[8] + bf0,bf1 reads | stage B(kt+1) ----------------
        short8 af[8];
#pragma unroll
        for (int i = 0; i < 8; ++i) af[i] = lds8(As + i * 512 + lane * 8);
        short8 bf0 = lds8(Bs + ((wc * 4 + 0) & 7) * 512 + lane * 8);
        short8 bf1 = lds8(Bs + ((wc * 4 + 1) & 7) * 512 + lane * 8);
        if (kt + 1 < NKT) { STB(kt + 1, 0); STB(kt + 1, 1); }
        __builtin_amdgcn_s_barrier();
        asm volatile("" ::: "memory");
        __builtin_amdgcn_s_setprio(1);
#pragma unroll
        for (int i = 0; i < 8; ++i) {
            acc[i][0] = MFMA16(af[i], bf0, acc[i][0]);
            acc[i][1] = MFMA16(af[i], bf1, acc[i][1]);
        }
        __builtin_amdgcn_s_setprio(0);
        __builtin_amdgcn_s_barrier();
        asm volatile("" ::: "memory");

        // ---------------- P1: bf2,bf3 reads | stage A(kt+2) ----------------
        short8 bf2 = lds8(Bs + ((wc * 4 + 2) & 7) * 512 + lane * 8);
        short8 bf3 = lds8(Bs + ((wc * 4 + 3) & 7) * 512 + lane * 8);
        if (kt + 2 < NKT) { STA(kt + 2, 0); STA(kt + 2, 1); }
        __builtin_amdgcn_s_barrier();
        asm volatile("" ::: "memory");
        __builtin_amdgcn_s_setprio(1);
#pragma unroll
        for (int i = 0; i < 8; ++i) {
            acc[i][2] = MFMA16(af[i], bf2, acc[i][2]);
            acc[i][3] = MFMA16(af[i], bf3, acc[i][3]);
        }
        __builtin_amdgcn_s_setprio(0);
        if (kt + 2 < NKT) asm volatile("s_waitcnt vmcnt(2)" ::: "memory");
        else              asm volatile("s_waitcnt vmcnt(0)" ::: "memory");
        __builtin_amdgcn_s_barrier();
        asm volatile("" ::: "memory");
    }
#undef STA
#undef STB

    float2* tabf = reinterpret_cast<float2*>(sm);
    if (EPI == 0) {
        // RoPE table over dead LDS: 256 t x 32 d2 float2 = 64 KiB
        const int t0 = (bm & 15) * 256;
        for (int e = tid; e < 8192; e += 512) {
            int tl = e >> 5, d2 = e & 31;
            float f = (float)(t0 + tl) * exp2f(-(float)d2 * 0.41524101186092f);
            float sn, cs; __sincosf(f, &sn, &cs);
            tabf[tl * 32 + d2] = make_float2(cs, sn);
        }
        __syncthreads();
    }

#pragma unroll
    for (int i = 0; i < 8; ++i)
#pragma unroll
        for (int j = 0; j < 4; ++j)
#pragma unroll
            for (int r = 0; r < 4; ++r) {
                int row = bm * 256 + wr * 128 + i * 16 + quad * 4 + r;
                int col = bn * 256 + wc * 64 + j * 16 + l15;
                float v = acc[i][j][r];
                if (EPI == 0) {
                    float p = __shfl_xor(v, 1);
                    int t_ = row & 4095, b_ = row >> 12;
                    int hh = col >> 6, d_ = col & 63;
                    int tl = wr * 128 + i * 16 + quad * 4 + r;
                    float2 cspair = tabf[tl * 32 + (d_ >> 1)];
                    float o = (d_ & 1) ? (p * cspair.y + v * cspair.x)
                                       : (v * cspair.x - p * cspair.y);
                    o *= QSCALE;
                    float po = __shfl_xor(o, 1);
                    if (!(lane & 1)) {
                        unsigned int pk = (unsigned int)f2bf(o) |
                                          ((unsigned int)f2bf(po) << 16);
                        *reinterpret_cast<unsigned int*>(
                            Cb + ((size_t)((b_ * 32 + hh) * 4096 + t_)) * 64 + d_) = pk;
                    }
                } else {
                    Cf[(size_t)row * 2048 + col] = v;
                }
            }
}

// ---------------- flash attention over 1024-key window ----------------
// Swapped-operand form (T12) + in-register P repack; 512-thread / 8-wave
// blocks covering 128 queries; K/V LDS tiles shared by 8 waves.
__global__ __launch_bounds__(512, 8)
void attn(const unsigned short* __restrict__ Q,
          const unsigned short* __restrict__ Kw,
          const unsigned short* __restrict__ Vt,
          unsigned short* __restrict__ O) {
    const int blk  = blockIdx.x;
    const int qblk = blk & 31;          // 32 blocks of 128 queries
    const int bh   = blk >> 5;
    const int h    = bh & 31;
    const int b    = bh >> 5;
    const int kvh  = h >> 2;

    const int tid  = threadIdx.x;
    const int lane = tid & 63;
    const int l15  = lane & 15;
    const int quad = lane >> 4;
    const int wid  = tid >> 6;          // 0..7
    const int qt0  = qblk * 128 + wid * 16;

    const unsigned short* Qp = Q  + ((size_t)bh * 4096 + qt0) * 64;
    const unsigned short* Kp = Kw + (size_t)(b * 8 + kvh) * 1024 * 64;
    const unsigned short* Vp = Vt + (size_t)(b * 8 + kvh) * 64 * 1024;

    // [buf][frag(8) * 512 + lane*8]; frag (c*2+half) for K, (j*2+shalf) for V
    __shared__ unsigned short Ks[2][4096];
    __shared__ unsigned short Vs[2][4096];

    short8 qa0 = lds8(&Qp[l15 * 64 + quad * 8]);
    short8 qa1 = lds8(&Qp[l15 * 64 + 32 + quad * 8]);

    // staging: wave w stages K frag f=w (chunk c=w>>1, k-half w&1) and
    // V frag f=w (d-group j=w>>1, key-half w&1)
    const unsigned short* gK = Kp + (size_t)((wid >> 1) * 16 + l15) * 64
                                  + (wid & 1) * 32 + quad * 8;
    const unsigned short* gV = Vp + (size_t)((wid >> 1) * 16 + l15) * 1024
                                  + (wid & 1) * 32 + quad * 8;
    unsigned short* sK0 = &Ks[0][wid * 512];
    unsigned short* sK1 = &Ks[1][wid * 512];
    unsigned short* sV0 = &Vs[0][wid * 512];
    unsigned short* sV1 = &Vs[1][wid * 512];

    const int ntiles = (qblk < 7 ? 2 * qblk + 2 : 16);      // block-uniform
    const int nkW    = (qt0 + 16 < 1024) ? qt0 + 16 : 1024; // per-wave keys
    const int ntW    = (nkW + 63) >> 6;                     // wave's tile count
    const bool diagW = (qt0 < 1024);

    // prefetch tile 0
    g2l16(gK, sK0);
    g2l16(gV, sV0);

    floatx4 o0 = {0,0,0,0}, o1 = {0,0,0,0}, o2 = {0,0,0,0}, o3 = {0,0,0,0};
    float Lq = 0.f;
    float m = -INFINITY;

    for (int it = 0; it < ntiles; ++it) {
        __syncthreads();                         // staging of tile `it` complete
        const int cur = it & 1;
        if (it + 1 < ntiles) {                   // prefetch next into other buffer
            g2l16(gK + (it + 1) * 4096, cur ? sK0 : sK1);
            g2l16(gV + (it + 1) * 64,   cur ? sV0 : sV1);
        }
        if (it >= ntW) continue;                 // wave done (barriers stay uniform)
        const int s0 = it << 6;
        const unsigned short* Kc = Ks[cur];
        const unsigned short* Vc = Vs[cur];

        // S^T = K·Q^T: lane holds S[key = s0 + c*16 + quad*4 + r][query = qt0 + l15]
        floatx4 sS[4];
#pragma unroll
        for (int c = 0; c < 4; ++c) {
            floatx4 z = {0, 0, 0, 0};
            z = MFMA16(lds8(Kc + c * 1024 + lane * 8), qa0, z);
            z = MFMA16(lds8(Kc + c * 1024 + 512 + lane * 8), qa1, z);
            sS[c] = z;
        }

        const bool last = (it == ntW - 1);
        bool skipHi = false;
        if (last && diagW) {                     // diagonal tile: causal mask
#pragma unroll
            for (int c = 0; c < 4; ++c)
#pragma unroll
                for (int r = 0; r < 4; ++r)
                    if (s0 + c * 16 + quad * 4 + r > qt0 + l15) sS[c][r] = -INFINITY;
            skipHi = (nkW - s0 <= 32);
        }

        // per-query tile max: max3 tree + quad reduce (keys live on quad bits)
        float t0 = fmaxf(fmaxf(sS[0][0], sS[0][1]), fmaxf(sS[0][2], sS[0][3]));
        float t1 = fmaxf(fmaxf(sS[1][0], sS[1][1]), fmaxf(sS[1][2], sS[1][3]));
        float t2 = fmaxf(fmaxf(sS[2][0], sS[2][1]), fmaxf(sS[2][2], sS[2][3]));
        float t3 = fmaxf(fmaxf(sS[3][0], sS[3][1]), fmaxf(sS[3][2], sS[3][3]));
        float mx = fmaxf(fmaxf(t0, t1), fmaxf(t2, t3));
        mx = fmaxf(mx, __shfl_xor(mx, 16));
        mx = fmaxf(mx, __shfl_xor(mx, 32));      // quad-uniform per query l15

        // defer-max (T13): only rescale when tile max exceeds m by > 8
        if (!__all(mx <= m + 8.0f)) {
            const float mn = fmaxf(m, mx);       // quad-uniform per query
            const float alpha = exp2f(m - mn);   // m=-inf first tile -> alpha=0
            m = mn;
            o0 *= alpha; o1 *= alpha; o2 *= alpha; o3 *= alpha;
            Lq *= alpha;
        }

        float p[4][4];
#pragma unroll
        for (int c = 0; c < 4; ++c)
#pragma unroll
            for (int r = 0; r < 4; ++r) p[c][r] = exp2f(sS[c][r] - m);
        Lq += ((p[0][0] + p[0][1] + p[0][2] + p[0][3]) + (p[1][0] + p[1][1] + p[1][2] + p[1][3]))
            + ((p[2][0] + p[2][1] + p[2][2] + p[2][3]) + (p[3][0] + p[3][1] + p[3][2] + p[3][3]));

        // in-register P repack: keys 0-31 (chunks 0,1) -> pa_lo
        unsigned int a0 = cvtpk(p[0][0], p[0][1]);
        unsigned int a1 = cvtpk(p[0][2], p[0][3]);
        unsigned int a2 = cvtpk(p[1][0], p[1][1]);
        unsigned int a3 = cvtpk(p[1][2], p[1][3]);
        pl32swap(a0, a2); pl32swap(a1, a3);
        pl16swap(a0, a2); pl16swap(a1, a3);
        uintx4 tlo = {a0, a1, a2, a3};
        short8 pa_lo = __builtin_bit_cast(short8, tlo);

        // O^T += V^T · P^T : A-frag = V^T (same LDS frags), B-frag = pa
        o0 = MFMA16(lds8(Vc + 0 * 512 + lane * 8), pa_lo, o0);
        o1 = MFMA16(lds8(Vc + 2 * 512 + lane * 8), pa_lo, o1);
        o2 = MFMA16(lds8(Vc + 4 * 512 + lane * 8), pa_lo, o2);
        o3 = MFMA16(lds8(Vc + 6 * 512 + lane * 8), pa_lo, o3);
        if (!skipHi) {
            // keys 32-63 (chunks 2,3) -> pa_hi
            unsigned int b0 = cvtpk(p[2][0], p[2][1]);
            unsigned int b1 = cvtpk(p[2][2], p[2][3]);
            unsigned int b2 = cvtpk(p[3][0], p[3][1]);
            unsigned int b3 = cvtpk(p[3][2], p[3][3]);
            pl32swap(b0, b2); pl32swap(b1, b3);
            pl16swap(b0, b2); pl16swap(b1, b3);
            uintx4 thi = {b0, b1, b2, b3};
            short8 pa_hi = __builtin_bit_cast(short8, thi);
            o0 = MFMA16(lds8(Vc + 1 * 512 + lane * 8), pa_hi, o0);
            o1 = MFMA16(lds8(Vc + 3 * 512 + lane * 8), pa_hi, o1);
            o2 = MFMA16(lds8(Vc + 5 * 512 + lane * 8), pa_hi, o2);
            o3 = MFMA16(lds8(Vc + 7 * 512 + lane * 8), pa_hi, o3);
        }
    }

    // Lq holds this lane's keys only; total = sum across quads
    Lq += __shfl_xor(Lq, 16);
    Lq += __shfl_xor(Lq, 32);
    const float inv = 1.f / Lq;

    // O^T layout: lane holds O[q = qt0+l15][d = j*16 + quad*4 + r] -> 8B stores
    unsigned short* Op = O + (size_t)b * 4096 * 2048 + (size_t)(qt0 + l15) * 2048
                           + h * 64 + quad * 4;
    uintx2 w0, w1, w2, w3;
    w0.x = cvtpk(o0[0] * inv, o0[1] * inv); w0.y = cvtpk(o0[2] * inv, o0[3] * inv);
    w1.x = cvtpk(o1[0] * inv, o1[1] * inv); w1.y = cvtpk(o1[2] * inv, o1[3] * inv);
    w2.x = cvtpk(o2[0] * inv, o2[1] * inv); w2.y = cvtpk(o2[2] * inv, o2[3] * inv);
    w3.x = cvtpk(o3[0] * inv, o3[1] * inv); w3.y = cvtpk(o3[2] * inv, o3[3] * inv);
    *reinterpret_cast<uintx2*>(Op)      = w0;
    *reinterpret_cast<uintx2*>(Op + 16) = w1;
    *reinterpret_cast<uintx2*>(Op + 32) = w2;
    *reinterpret_cast<uintx2*>(Op + 48) = w3;
}

// ---------------- launch ----------------
extern "C" void kernel_launch(void* const* d_in, const int* in_sizes, int n_in,
                              void* d_out, int out_size, void* d_ws, size_t ws_size,
                              hipStream_t stream) {
    const float* x  = (const float*)d_in[0];
    const float* kc = (const float*)d_in[1];
    const float* vc = (const float*)d_in[2];
    const float* Wq = (const float*)d_in[3];
    const float* Wo = (const float*)d_in[4];
    float* out = (float*)d_out;

    char* ws = (char*)d_ws;
    unsigned short* Xb  = (unsigned short*)(ws);              // 33,554,432 B (reused as O)
    unsigned short* Qb  = (unsigned short*)(ws + 33554432);   // 33,554,432 B
    unsigned short* Wqb = (unsigned short*)(ws + 67108864);   //  8,388,608 B
    unsigned short* Wob = (unsigned short*)(ws + 75497472);   //  8,388,608 B
    unsigned short* Kwb = (unsigned short*)(ws + 83886080);   //  2,097,152 B
    unsigned short* Vtb = (unsigned short*)(ws + 85983232);   //  2,097,152 B

    cvt_bf16<<<16384, 256, 0, stream>>>(x,  Xb,  4194304);
    cvt_bf16<<<4096,  256, 0, stream>>>(Wq, Wqb, 1048576);
    cvt_bf16<<<4096,  256, 0, stream>>>(Wo, Wob, 1048576);
    prep_k<<<1024, 256, 0, stream>>>(kc, Kwb);
    prep_v<<<256, 256, 0, stream>>>(vc, Vtb);

    gemm8p<0><<<256, 512, 0, stream>>>(Xb, Wqb, nullptr, Qb);   // Q + RoPE (pre-scaled)
    attn<<<2048, 512, 0, stream>>>(Qb, Kwb, Vtb, Xb);           // O -> Xb
    gemm8p<1><<<256, 512, 0, stream>>>(Xb, Wob, out, nullptr);  // out proj
}

// Round 7
// 442.169 us; speedup vs baseline: 1.0313x; 1.0313x over previous
//
#include <hip/hip_runtime.h>
#include <math.h>

typedef __attribute__((ext_vector_type(8))) short short8;
typedef __attribute__((ext_vector_type(4))) float floatx4;
typedef __attribute__((ext_vector_type(4))) unsigned int uintx4;
typedef __attribute__((ext_vector_type(2))) unsigned int uintx2;

#define MFMA16(a, b, c) __builtin_amdgcn_mfma_f32_16x16x32_bf16((a), (b), (c), 0, 0, 0)

// log2(e) * (1/sqrt(64)) — folded into Q so attention works in exp2 domain
#define QSCALE 0.18033688011112042f

__device__ __forceinline__ unsigned short f2bf(float x) {
    unsigned int u = __float_as_uint(x);
    u += 0x7fffu + ((u >> 16) & 1u);   // round-to-nearest-even
    return (unsigned short)(u >> 16);
}

__device__ __forceinline__ short8 lds8(const unsigned short* p) {
    return *reinterpret_cast<const short8*>(p);
}

// async global->LDS, 16B per lane; LDS dest = wave-uniform base + lane*16
__device__ __forceinline__ void g2l16(const unsigned short* g, unsigned short* l) {
    __builtin_amdgcn_global_load_lds(
        (const __attribute__((address_space(1))) unsigned int*)g,
        (__attribute__((address_space(3))) unsigned int*)l,
        16, 0, 0);
}

// pack two f32 -> bf16x2 dword (RNE): low = a, high = b
__device__ __forceinline__ unsigned int cvtpk(float a, float b) {
    unsigned int r;
    asm("v_cvt_pk_bf16_f32 %0, %1, %2" : "=v"(r) : "v"(a), "v"(b));
    return r;
}

// swap lanes[32:63] of a with lanes[0:31] of b (both modified)
__device__ __forceinline__ void pl32swap(unsigned int& a, unsigned int& b) {
    asm("v_permlane32_swap_b32 %0, %1" : "+v"(a), "+v"(b));
}

// swap odd 16-lane groups of a with even 16-lane groups of b (both modified)
__device__ __forceinline__ void pl16swap(unsigned int& a, unsigned int& b) {
    asm("v_permlane16_swap_b32 %0, %1" : "+v"(a), "+v"(b));
}

// ---------------- prep: fp32 -> bf16 convert (vectorized) ----------------
__global__ void cvt_bf16(const float* __restrict__ src, unsigned short* __restrict__ dst, int n4) {
    int i = blockIdx.x * blockDim.x + threadIdx.x;
    if (i >= n4) return;
    float4 v = reinterpret_cast<const float4*>(src)[i];
    ushort4 o;
    o.x = f2bf(v.x); o.y = f2bf(v.y); o.z = f2bf(v.z); o.w = f2bf(v.w);
    reinterpret_cast<ushort4*>(dst)[i] = o;
}

// ---------------- prep: K window convert (coalesced both sides) ----------------
__global__ void prep_k(const float* __restrict__ kc, unsigned short* __restrict__ Kw) {
    int i = blockIdx.x * blockDim.x + threadIdx.x;   // 0 .. 262143
    int d4  = (i & 15) * 4;
    int s   = (i >> 4) & 1023;
    int bkv = i >> 14;
    size_t src = ((size_t)bkv * 4096 + 3072 + s) * 64 + d4;
    float4 kv = *reinterpret_cast<const float4*>(kc + src);
    ushort4 ko;
    ko.x = f2bf(kv.x); ko.y = f2bf(kv.y); ko.z = f2bf(kv.z); ko.w = f2bf(kv.w);
    *reinterpret_cast<ushort4*>(Kw + ((size_t)bkv * 1024 + s) * 64 + d4) = ko;
}

// ---------------- prep: V window transpose via LDS tile ----------------
__global__ void prep_v(const float* __restrict__ vc, unsigned short* __restrict__ Vt) {
    __shared__ unsigned short tl[64][72];
    const int bkv = blockIdx.x >> 4;
    const int s0  = (blockIdx.x & 15) * 64;
    const int t   = threadIdx.x;
    const int sl  = t >> 2;
    const int dq  = (t & 3) * 16;
    const float* src = vc + ((size_t)bkv * 4096 + 3072 + s0 + sl) * 64 + dq;
    float4 v0 = reinterpret_cast<const float4*>(src)[0];
    float4 v1 = reinterpret_cast<const float4*>(src)[1];
    float4 v2 = reinterpret_cast<const float4*>(src)[2];
    float4 v3 = reinterpret_cast<const float4*>(src)[3];
    tl[dq +  0][sl] = f2bf(v0.x); tl[dq +  1][sl] = f2bf(v0.y);
    tl[dq +  2][sl] = f2bf(v0.z); tl[dq +  3][sl] = f2bf(v0.w);
    tl[dq +  4][sl] = f2bf(v1.x); tl[dq +  5][sl] = f2bf(v1.y);
    tl[dq +  6][sl] = f2bf(v1.z); tl[dq +  7][sl] = f2bf(v1.w);
    tl[dq +  8][sl] = f2bf(v2.x); tl[dq +  9][sl] = f2bf(v2.y);
    tl[dq + 10][sl] = f2bf(v2.z); tl[dq + 11][sl] = f2bf(v2.w);
    tl[dq + 12][sl] = f2bf(v3.x); tl[dq + 13][sl] = f2bf(v3.y);
    tl[dq + 14][sl] = f2bf(v3.z); tl[dq + 15][sl] = f2bf(v3.w);
    __syncthreads();
    const int dl = t >> 2;
    const int sc = (t & 3) * 16;
    unsigned short* dst = Vt + ((size_t)bkv * 64 + dl) * 1024 + s0 + sc;
    short8 x0 = *reinterpret_cast<const short8*>(&tl[dl][sc]);
    short8 x1 = *reinterpret_cast<const short8*>(&tl[dl][sc + 8]);
    *reinterpret_cast<short8*>(dst)     = x0;
    *reinterpret_cast<short8*>(dst + 8) = x1;
}

// ---------------- bf16 MFMA GEMM, 256x256 tile, BK=32, 8 waves ----------------
// (R4 structure — best measured GEMM variant.) T3+T4 pipeline: raw s_barrier
// + counted vmcnt (stage tile t+2 while computing tile t; wait only tile t+1
// at iteration end). Fragment-order LDS: conflict-free g2l16/ds_read pair.
template <int EPI>
__global__ __launch_bounds__(512, 2)
void gemm256(const unsigned short* __restrict__ A,
             const unsigned short* __restrict__ Bt,
             float* __restrict__ Cf,
             unsigned short* __restrict__ Cb) {
    constexpr int K  = 2048;
    constexpr int NT = 64;                    // K / 32
    __shared__ unsigned short sm[32768];      // 2 bufs x 16384 ush

    const int tid  = threadIdx.x;
    const int lane = tid & 63;
    const int l15  = lane & 15;
    const int quad = lane >> 4;
    const int wid  = tid >> 6;                // 0..7
    const int wr   = wid >> 2;                // 0..1  (M half)
    const int wc   = wid & 3;                 // 0..3  (N quarter)

    const int bn = blockIdx.x & 7;            // XCD-friendly B-panel mapping
    const int bm = blockIdx.x >> 3;

    const unsigned short* gA0 = A  + (size_t)(bm * 256 + 2 * wid * 16 + l15) * K + quad * 8;
    const unsigned short* gA1 = gA0 + (size_t)16 * K;
    const unsigned short* gB0 = Bt + (size_t)(bn * 256 + 2 * wid * 16 + l15) * K + quad * 8;
    const unsigned short* gB1 = gB0 + (size_t)16 * K;

    auto STAGE = [&](int t) {
        unsigned short* dst = sm + (t & 1) * 16384 + 2 * wid * 512;
        const int off = t * 32;
        g2l16(gA0 + off, dst);
        g2l16(gA1 + off, dst + 512);
        g2l16(gB0 + off, dst + 8192);
        g2l16(gB1 + off, dst + 8704);
    };

    floatx4 acc[8][4];
#pragma unroll
    for (int i = 0; i < 8; ++i)
#pragma unroll
        for (int j = 0; j < 4; ++j) acc[i][j] = floatx4{0, 0, 0, 0};

    STAGE(0);
    STAGE(1);
    asm volatile("s_waitcnt vmcnt(4)" ::: "memory");
    __builtin_amdgcn_s_barrier();
    asm volatile("" ::: "memory");

    for (int t = 0; t < NT; ++t) {
        const unsigned short* cb = sm + (t & 1) * 16384;

        short8 bf[4], af[8];
#pragma unroll
        for (int j = 0; j < 4; ++j)
            bf[j] = lds8(cb + 8192 + (wc * 4 + j) * 512 + lane * 8);
#pragma unroll
        for (int i = 0; i < 8; ++i)
            af[i] = lds8(cb + (wr * 8 + i) * 512 + lane * 8);

        asm volatile("s_waitcnt lgkmcnt(0)" ::: "memory");
        __builtin_amdgcn_s_barrier();         // all reads of tile t retired
        asm volatile("" ::: "memory");

        if (t + 2 < NT) STAGE(t + 2);         // overwrite dead regions of buf[t&1]

        __builtin_amdgcn_s_setprio(1);
#pragma unroll
        for (int i = 0; i < 8; ++i)
#pragma unroll
            for (int j = 0; j < 4; ++j)
                acc[i][j] = MFMA16(af[i], bf[j], acc[i][j]);
        __builtin_amdgcn_s_setprio(0);

        if (t + 2 < NT) asm volatile("s_waitcnt vmcnt(4)" ::: "memory");  // tile t+1 landed
        else            asm volatile("s_waitcnt vmcnt(0)" ::: "memory");
        __builtin_amdgcn_s_barrier();
        asm volatile("" ::: "memory");
    }

    float2* tabf = reinterpret_cast<float2*>(sm);
    if (EPI == 0) {
        // RoPE table over dead LDS: 256 t x 32 d2 float2 = 64 KiB
        const int t0 = (bm & 15) * 256;
        for (int e = tid; e < 8192; e += 512) {
            int tl = e >> 5, d2 = e & 31;
            float f = (float)(t0 + tl) * exp2f(-(float)d2 * 0.41524101186092f);
            float sn, cs; __sincosf(f, &sn, &cs);
            tabf[tl * 32 + d2] = make_float2(cs, sn);
        }
        __syncthreads();
    }

#pragma unroll
    for (int i = 0; i < 8; ++i)
#pragma unroll
        for (int j = 0; j < 4; ++j)
#pragma unroll
            for (int r = 0; r < 4; ++r) {
                int row = bm * 256 + wr * 128 + i * 16 + quad * 4 + r;
                int col = bn * 256 + wc * 64 + j * 16 + l15;
                float v = acc[i][j][r];
                if (EPI == 0) {
                    float p = __shfl_xor(v, 1);
                    int t_ = row & 4095, b_ = row >> 12;
                    int hh = col >> 6, d = col & 63;
                    int tl = wr * 128 + i * 16 + quad * 4 + r;
                    float2 cspair = tabf[tl * 32 + (d >> 1)];
                    float o = (d & 1) ? (p * cspair.y + v * cspair.x)
                                      : (v * cspair.x - p * cspair.y);
                    o *= QSCALE;
                    float po = __shfl_xor(o, 1);
                    if (!(lane & 1)) {
                        unsigned int pk = (unsigned int)f2bf(o) |
                                          ((unsigned int)f2bf(po) << 16);
                        *reinterpret_cast<unsigned int*>(
                            Cb + ((size_t)((b_ * 32 + hh) * 4096 + t_)) * 64 + d) = pk;
                    }
                } else {
                    Cf[(size_t)row * 2048 + col] = v;
                }
            }
}

// ---------------- flash attention over 1024-key window ----------------
// Swapped-operand form (T12) + in-register P repack; 512-thread / 8-wave
// blocks covering 128 queries; K/V LDS tiles shared by 8 waves.
// This round: L accumulated via MFMA ones-trick (B-frag pa holds the FULL
// 32-key P slice per query, so MFMA(ones, pa, La) gives La[r] = sum_k P[k][q]
// with zero cross-lane ops — deletes the 16-add L tree + final shuffles) and
// T5 setprio around the MFMA clusters (m191: +4-7% on attn).
__global__ __launch_bounds__(512, 8)
void attn(const unsigned short* __restrict__ Q,
          const unsigned short* __restrict__ Kw,
          const unsigned short* __restrict__ Vt,
          unsigned short* __restrict__ O) {
    const int blk  = blockIdx.x;
    const int qblk = blk & 31;          // 32 blocks of 128 queries
    const int bh   = blk >> 5;
    const int h    = bh & 31;
    const int b    = bh >> 5;
    const int kvh  = h >> 2;

    const int tid  = threadIdx.x;
    const int lane = tid & 63;
    const int l15  = lane & 15;
    const int quad = lane >> 4;
    const int wid  = tid >> 6;          // 0..7
    const int qt0  = qblk * 128 + wid * 16;

    const unsigned short* Qp = Q  + ((size_t)bh * 4096 + qt0) * 64;
    const unsigned short* Kp = Kw + (size_t)(b * 8 + kvh) * 1024 * 64;
    const unsigned short* Vp = Vt + (size_t)(b * 8 + kvh) * 64 * 1024;

    // [buf][frag(8) * 512 + lane*8]; frag (c*2+half) for K, (j*2+shalf) for V
    __shared__ unsigned short Ks[2][4096];
    __shared__ unsigned short Vs[2][4096];

    short8 qa0 = lds8(&Qp[l15 * 64 + quad * 8]);
    short8 qa1 = lds8(&Qp[l15 * 64 + 32 + quad * 8]);

    short8 ones;                         // bf16 1.0 x8 (A-frag of all-ones)
#pragma unroll
    for (int i = 0; i < 8; ++i) ones[i] = (short)0x3F80;

    // staging: wave w stages K frag f=w and V frag f=w
    const unsigned short* gK = Kp + (size_t)((wid >> 1) * 16 + l15) * 64
                                  + (wid & 1) * 32 + quad * 8;
    const unsigned short* gV = Vp + (size_t)((wid >> 1) * 16 + l15) * 1024
                                  + (wid & 1) * 32 + quad * 8;
    unsigned short* sK0 = &Ks[0][wid * 512];
    unsigned short* sK1 = &Ks[1][wid * 512];
    unsigned short* sV0 = &Vs[0][wid * 512];
    unsigned short* sV1 = &Vs[1][wid * 512];

    const int ntiles = (qblk < 7 ? 2 * qblk + 2 : 16);      // block-uniform
    const int nkW    = (qt0 + 16 < 1024) ? qt0 + 16 : 1024; // per-wave keys
    const int ntW    = (nkW + 63) >> 6;                     // wave's tile count
    const bool diagW = (qt0 < 1024);

    // prefetch tile 0
    g2l16(gK, sK0);
    g2l16(gV, sV0);

    floatx4 o0 = {0,0,0,0}, o1 = {0,0,0,0}, o2 = {0,0,0,0}, o3 = {0,0,0,0};
    floatx4 La = {0,0,0,0};
    float m = -INFINITY;

    for (int it = 0; it < ntiles; ++it) {
        __syncthreads();                         // staging of tile `it` complete
        const int cur = it & 1;
        if (it + 1 < ntiles) {                   // prefetch next into other buffer
            g2l16(gK + (it + 1) * 4096, cur ? sK0 : sK1);
            g2l16(gV + (it + 1) * 64,   cur ? sV0 : sV1);
        }
        if (it >= ntW) continue;                 // wave done (barriers stay uniform)
        const int s0 = it << 6;
        const unsigned short* Kc = Ks[cur];
        const unsigned short* Vc = Vs[cur];

        // S^T = K·Q^T: lane holds S[key = s0 + c*16 + quad*4 + r][query = qt0 + l15]
        floatx4 sS[4];
        __builtin_amdgcn_s_setprio(1);
#pragma unroll
        for (int c = 0; c < 4; ++c) {
            floatx4 z = {0, 0, 0, 0};
            z = MFMA16(lds8(Kc + c * 1024 + lane * 8), qa0, z);
            z = MFMA16(lds8(Kc + c * 1024 + 512 + lane * 8), qa1, z);
            sS[c] = z;
        }
        __builtin_amdgcn_s_setprio(0);

        const bool last = (it == ntW - 1);
        bool skipHi = false;
        if (last && diagW) {                     // diagonal tile: causal mask
#pragma unroll
            for (int c = 0; c < 4; ++c)
#pragma unroll
                for (int r = 0; r < 4; ++r)
                    if (s0 + c * 16 + quad * 4 + r > qt0 + l15) sS[c][r] = -INFINITY;
            skipHi = (nkW - s0 <= 32);
        }

        // per-query tile max: max3 tree + quad reduce (keys live on quad bits)
        float t0 = fmaxf(fmaxf(sS[0][0], sS[0][1]), fmaxf(sS[0][2], sS[0][3]));
        float t1 = fmaxf(fmaxf(sS[1][0], sS[1][1]), fmaxf(sS[1][2], sS[1][3]));
        float t2 = fmaxf(fmaxf(sS[2][0], sS[2][1]), fmaxf(sS[2][2], sS[2][3]));
        float t3 = fmaxf(fmaxf(sS[3][0], sS[3][1]), fmaxf(sS[3][2], sS[3][3]));
        float mx = fmaxf(fmaxf(t0, t1), fmaxf(t2, t3));
        mx = fmaxf(mx, __shfl_xor(mx, 16));
        mx = fmaxf(mx, __shfl_xor(mx, 32));      // quad-uniform per query l15

        // defer-max (T13): only rescale when tile max exceeds m by > 8
        if (!__all(mx <= m + 8.0f)) {
            const float mn = fmaxf(m, mx);       // quad-uniform per query
            const float alpha = exp2f(m - mn);   // m=-inf first tile -> alpha=0
            m = mn;
            o0 *= alpha; o1 *= alpha; o2 *= alpha; o3 *= alpha;
            La *= alpha;
        }

        float p[4][4];
#pragma unroll
        for (int c = 0; c < 4; ++c)
#pragma unroll
            for (int r = 0; r < 4; ++r) p[c][r] = exp2f(sS[c][r] - m);

        // in-register P repack: keys 0-31 (chunks 0,1) -> pa_lo
        unsigned int a0 = cvtpk(p[0][0], p[0][1]);
        unsigned int a1 = cvtpk(p[0][2], p[0][3]);
        unsigned int a2 = cvtpk(p[1][0], p[1][1]);
        unsigned int a3 = cvtpk(p[1][2], p[1][3]);
        pl32swap(a0, a2); pl32swap(a1, a3);
        pl16swap(a0, a2); pl16swap(a1, a3);
        uintx4 tlo = {a0, a1, a2, a3};
        short8 pa_lo = __builtin_bit_cast(short8, tlo);

        // O^T += V^T · P^T ; L += ones · P^T (full 32-key sum per query)
        __builtin_amdgcn_s_setprio(1);
        o0 = MFMA16(lds8(Vc + 0 * 512 + lane * 8), pa_lo, o0);
        o1 = MFMA16(lds8(Vc + 2 * 512 + lane * 8), pa_lo, o1);
        o2 = MFMA16(lds8(Vc + 4 * 512 + lane * 8), pa_lo, o2);
        o3 = MFMA16(lds8(Vc + 6 * 512 + lane * 8), pa_lo, o3);
        La = MFMA16(ones, pa_lo, La);
        __builtin_amdgcn_s_setprio(0);
        if (!skipHi) {
            // keys 32-63 (chunks 2,3) -> pa_hi
            unsigned int b0 = cvtpk(p[2][0], p[2][1]);
            unsigned int b1 = cvtpk(p[2][2], p[2][3]);
            unsigned int b2 = cvtpk(p[3][0], p[3][1]);
            unsigned int b3 = cvtpk(p[3][2], p[3][3]);
            pl32swap(b0, b2); pl32swap(b1, b3);
            pl16swap(b0, b2); pl16swap(b1, b3);
            uintx4 thi = {b0, b1, b2, b3};
            short8 pa_hi = __builtin_bit_cast(short8, thi);
            __builtin_amdgcn_s_setprio(1);
            o0 = MFMA16(lds8(Vc + 1 * 512 + lane * 8), pa_hi, o0);
            o1 = MFMA16(lds8(Vc + 3 * 512 + lane * 8), pa_hi, o1);
            o2 = MFMA16(lds8(Vc + 5 * 512 + lane * 8), pa_hi, o2);
            o3 = MFMA16(lds8(Vc + 7 * 512 + lane * 8), pa_hi, o3);
            La = MFMA16(ones, pa_hi, La);
            __builtin_amdgcn_s_setprio(0);
        }
    }

    const float inv = 1.f / La[0];      // all 4 entries equal (full key sum)

    // O^T layout: lane holds O[q = qt0+l15][d = j*16 + quad*4 + r] -> 8B stores
    unsigned short* Op = O + (size_t)b * 4096 * 2048 + (size_t)(qt0 + l15) * 2048
                           + h * 64 + quad * 4;
    uintx2 w0, w1, w2, w3;
    w0.x = cvtpk(o0[0] * inv, o0[1] * inv); w0.y = cvtpk(o0[2] * inv, o0[3] * inv);
    w1.x = cvtpk(o1[0] * inv, o1[1] * inv); w1.y = cvtpk(o1[2] * inv, o1[3] * inv);
    w2.x = cvtpk(o2[0] * inv, o2[1] * inv); w2.y = cvtpk(o2[2] * inv, o2[3] * inv);
    w3.x = cvtpk(o3[0] * inv, o3[1] * inv); w3.y = cvtpk(o3[2] * inv, o3[3] * inv);
    *reinterpret_cast<uintx2*>(Op)      = w0;
    *reinterpret_cast<uintx2*>(Op + 16) = w1;
    *reinterpret_cast<uintx2*>(Op + 32) = w2;
    *reinterpret_cast<uintx2*>(Op + 48) = w3;
}

// ---------------- launch ----------------
extern "C" void kernel_launch(void* const* d_in, const int* in_sizes, int n_in,
                              void* d_out, int out_size, void* d_ws, size_t ws_size,
                              hipStream_t stream) {
    const float* x  = (const float*)d_in[0];
    const float* kc = (const float*)d_in[1];
    const float* vc = (const float*)d_in[2];
    const float* Wq = (const float*)d_in[3];
    const float* Wo = (const float*)d_in[4];
    float* out = (float*)d_out;

    char* ws = (char*)d_ws;
    unsigned short* Xb  = (unsigned short*)(ws);              // 33,554,432 B (reused as O)
    unsigned short* Qb  = (unsigned short*)(ws + 33554432);   // 33,554,432 B
    unsigned short* Wqb = (unsigned short*)(ws + 67108864);   //  8,388,608 B
    unsigned short* Wob = (unsigned short*)(ws + 75497472);   //  8,388,608 B
    unsigned short* Kwb = (unsigned short*)(ws + 83886080);   //  2,097,152 B
    unsigned short* Vtb = (unsigned short*)(ws + 85983232);   //  2,097,152 B

    cvt_bf16<<<16384, 256, 0, stream>>>(x,  Xb,  4194304);
    cvt_bf16<<<4096,  256, 0, stream>>>(Wq, Wqb, 1048576);
    cvt_bf16<<<4096,  256, 0, stream>>>(Wo, Wob, 1048576);
    prep_k<<<1024, 256, 0, stream>>>(kc, Kwb);
    prep_v<<<256, 256, 0, stream>>>(vc, Vtb);

    gemm256<0><<<256, 512, 0, stream>>>(Xb, Wqb, nullptr, Qb);   // Q + RoPE (pre-scaled)
    attn<<<2048, 512, 0, stream>>>(Qb, Kwb, Vtb, Xb);            // O -> Xb
    gemm256<1><<<256, 512, 0, stream>>>(Xb, Wob, out, nullptr);  // out proj
}

// Round 8
// 442.050 us; speedup vs baseline: 1.0316x; 1.0003x over previous
//
#include <hip/hip_runtime.h>
#include <math.h>

typedef __attribute__((ext_vector_type(8))) short short8;
typedef __attribute__((ext_vector_type(4))) float floatx4;
typedef __attribute__((ext_vector_type(4))) unsigned int uintx4;
typedef __attribute__((ext_vector_type(2))) unsigned int uintx2;

#define MFMA16(a, b, c) __builtin_amdgcn_mfma_f32_16x16x32_bf16((a), (b), (c), 0, 0, 0)

// log2(e) * (1/sqrt(64)) — folded into Q so attention works in exp2 domain
#define QSCALE 0.18033688011112042f

__device__ __forceinline__ unsigned short f2bf(float x) {
    unsigned int u = __float_as_uint(x);
    u += 0x7fffu + ((u >> 16) & 1u);   // round-to-nearest-even
    return (unsigned short)(u >> 16);
}

__device__ __forceinline__ short8 lds8(const unsigned short* p) {
    return *reinterpret_cast<const short8*>(p);
}

// async global->LDS, 16B per lane; LDS dest = wave-uniform base + lane*16
__device__ __forceinline__ void g2l16(const unsigned short* g, unsigned short* l) {
    __builtin_amdgcn_global_load_lds(
        (const __attribute__((address_space(1))) unsigned int*)g,
        (__attribute__((address_space(3))) unsigned int*)l,
        16, 0, 0);
}

// pack two f32 -> bf16x2 dword (RNE): low = a, high = b
__device__ __forceinline__ unsigned int cvtpk(float a, float b) {
    unsigned int r;
    asm("v_cvt_pk_bf16_f32 %0, %1, %2" : "=v"(r) : "v"(a), "v"(b));
    return r;
}

// swap lanes[32:63] of a with lanes[0:31] of b (both modified)
__device__ __forceinline__ void pl32swap(unsigned int& a, unsigned int& b) {
    asm("v_permlane32_swap_b32 %0, %1" : "+v"(a), "+v"(b));
}

// swap odd 16-lane groups of a with even 16-lane groups of b (both modified)
__device__ __forceinline__ void pl16swap(unsigned int& a, unsigned int& b) {
    asm("v_permlane16_swap_b32 %0, %1" : "+v"(a), "+v"(b));
}

// ---------------- prep: fp32 -> bf16 convert (vectorized) ----------------
__global__ void cvt_bf16(const float* __restrict__ src, unsigned short* __restrict__ dst, int n4) {
    int i = blockIdx.x * blockDim.x + threadIdx.x;
    if (i >= n4) return;
    float4 v = reinterpret_cast<const float4*>(src)[i];
    ushort4 o;
    o.x = f2bf(v.x); o.y = f2bf(v.y); o.z = f2bf(v.z); o.w = f2bf(v.w);
    reinterpret_cast<ushort4*>(dst)[i] = o;
}

// ---------------- prep: K window convert (coalesced both sides) ----------------
__global__ void prep_k(const float* __restrict__ kc, unsigned short* __restrict__ Kw) {
    int i = blockIdx.x * blockDim.x + threadIdx.x;   // 0 .. 262143
    int d4  = (i & 15) * 4;
    int s   = (i >> 4) & 1023;
    int bkv = i >> 14;
    size_t src = ((size_t)bkv * 4096 + 3072 + s) * 64 + d4;
    float4 kv = *reinterpret_cast<const float4*>(kc + src);
    ushort4 ko;
    ko.x = f2bf(kv.x); ko.y = f2bf(kv.y); ko.z = f2bf(kv.z); ko.w = f2bf(kv.w);
    *reinterpret_cast<ushort4*>(Kw + ((size_t)bkv * 1024 + s) * 64 + d4) = ko;
}

// ---------------- prep: V window transpose via LDS tile ----------------
__global__ void prep_v(const float* __restrict__ vc, unsigned short* __restrict__ Vt) {
    __shared__ unsigned short tl[64][72];
    const int bkv = blockIdx.x >> 4;
    const int s0  = (blockIdx.x & 15) * 64;
    const int t   = threadIdx.x;
    const int sl  = t >> 2;
    const int dq  = (t & 3) * 16;
    const float* src = vc + ((size_t)bkv * 4096 + 3072 + s0 + sl) * 64 + dq;
    float4 v0 = reinterpret_cast<const float4*>(src)[0];
    float4 v1 = reinterpret_cast<const float4*>(src)[1];
    float4 v2 = reinterpret_cast<const float4*>(src)[2];
    float4 v3 = reinterpret_cast<const float4*>(src)[3];
    tl[dq +  0][sl] = f2bf(v0.x); tl[dq +  1][sl] = f2bf(v0.y);
    tl[dq +  2][sl] = f2bf(v0.z); tl[dq +  3][sl] = f2bf(v0.w);
    tl[dq +  4][sl] = f2bf(v1.x); tl[dq +  5][sl] = f2bf(v1.y);
    tl[dq +  6][sl] = f2bf(v1.z); tl[dq +  7][sl] = f2bf(v1.w);
    tl[dq +  8][sl] = f2bf(v2.x); tl[dq +  9][sl] = f2bf(v2.y);
    tl[dq + 10][sl] = f2bf(v2.z); tl[dq + 11][sl] = f2bf(v2.w);
    tl[dq + 12][sl] = f2bf(v3.x); tl[dq + 13][sl] = f2bf(v3.y);
    tl[dq + 14][sl] = f2bf(v3.z); tl[dq + 15][sl] = f2bf(v3.w);
    __syncthreads();
    const int dl = t >> 2;
    const int sc = (t & 3) * 16;
    unsigned short* dst = Vt + ((size_t)bkv * 64 + dl) * 1024 + s0 + sc;
    short8 x0 = *reinterpret_cast<const short8*>(&tl[dl][sc]);
    short8 x1 = *reinterpret_cast<const short8*>(&tl[dl][sc + 8]);
    *reinterpret_cast<short8*>(dst)     = x0;
    *reinterpret_cast<short8*>(dst + 8) = x1;
}

// ---------------- bf16 MFMA GEMM, 256x256 tile, BK=64, 8-phase (m201-style) ----------------
// LDS 128 KiB: A = [buf(2)][kh(2)][subtile r(16)][512 ush], B same at +32768.
// Fragment-order subtiles: lane l of subtile holds row l15, k-chunk quad —
// g2l16 (linear dest) and ds_read_b128 (lane-linear) conflict-free, no swizzle.
// Per K-tile (BK=64): 8 phases, each {ds_read (2-6) || 1 stage call -> barrier
// -> lgkmcnt(0) -> setprio 8 MFMA setprio -> barrier}; counted vmcnt(8) at
// phases 3 and 7 only (T4 — never 0 mid-loop). Stage schedule (liveness-proven):
//   ph0-3 of kt stage (kt+1,kh1) into buf d^1 kh1 (readers retired kt-1 ph4-7);
//   ph4-7 of kt stage (kt+2,kh0) into buf d kh0 (readers retired kt ph0-3).
// vmcnt(8): ph3 retires (kt,kh1) of 12 outstanding; ph7 retires (kt+1,kh0).
template <int EPI>
__global__ __launch_bounds__(512, 2)
void gemmk(const unsigned short* __restrict__ A,
           const unsigned short* __restrict__ Bt,
           float* __restrict__ Cf,
           unsigned short* __restrict__ Cb) {
    constexpr int K   = 2048;
    constexpr int NKT = 32;                       // K / 64
    __shared__ __align__(16) unsigned short sm[65536];   // 128 KiB

    const int tid  = threadIdx.x;
    const int lane = tid & 63;
    const int l15  = lane & 15;
    const int quad = lane >> 4;
    const int wid  = tid >> 6;                    // 0..7
    const int wr   = wid >> 2;                    // M half
    const int wc   = wid & 3;                     // N quarter

    const int bn = blockIdx.x & 7;                // XCD x owns B-panel bn=x (1 MB, L2)
    const int bm = blockIdx.x >> 3;

    // per-lane base addresses (wave-uniform subtile offset added per call)
    const unsigned short* gAl = A  + (size_t)(bm * 256 + l15) * K + quad * 8;
    const unsigned short* gBl = Bt + (size_t)(bn * 256 + l15) * K + quad * 8;

    // stage subtile r = c*8+wid of (kt, kh); 1 g2l16 per wave = 1 KB
#define STG_A(kt, kh, c) g2l16(gAl + (size_t)((c) * 8 + wid) * 16 * K + (kt) * 64 + (kh) * 32, \
                               sm + ((kt) & 1) * 16384 + (kh) * 8192 + ((c) * 8 + wid) * 512)
#define STG_B(kt, kh, c) g2l16(gBl + (size_t)((c) * 8 + wid) * 16 * K + (kt) * 64 + (kh) * 32, \
                               sm + 32768 + ((kt) & 1) * 16384 + (kh) * 8192 + ((c) * 8 + wid) * 512)

    floatx4 acc[8][4];
#pragma unroll
    for (int i = 0; i < 8; ++i)
#pragma unroll
        for (int j = 0; j < 4; ++j) acc[i][j] = floatx4{0, 0, 0, 0};

    // prologue: (0,kh0) x4, (0,kh1) x4, (1,kh0) x4; wait oldest group
    STG_B(0, 0, 0); STG_B(0, 0, 1); STG_A(0, 0, 0); STG_A(0, 0, 1);
    STG_B(0, 1, 0); STG_B(0, 1, 1); STG_A(0, 1, 0); STG_A(0, 1, 1);
    STG_B(1, 0, 0); STG_B(1, 0, 1); STG_A(1, 0, 0); STG_A(1, 0, 1);
    asm volatile("s_waitcnt vmcnt(8)" ::: "memory");
    __builtin_amdgcn_s_barrier();
    asm volatile("" ::: "memory");

#define DO_MFMA(ip)                                                  \
    __builtin_amdgcn_s_setprio(1);                                   \
    acc[2*(ip)][0]   = MFMA16(af0, bf[0], acc[2*(ip)][0]);           \
    acc[2*(ip)][1]   = MFMA16(af0, bf[1], acc[2*(ip)][1]);           \
    acc[2*(ip)][2]   = MFMA16(af0, bf[2], acc[2*(ip)][2]);           \
    acc[2*(ip)][3]   = MFMA16(af0, bf[3], acc[2*(ip)][3]);           \
    acc[2*(ip)+1][0] = MFMA16(af1, bf[0], acc[2*(ip)+1][0]);         \
    acc[2*(ip)+1][1] = MFMA16(af1, bf[1], acc[2*(ip)+1][1]);         \
    acc[2*(ip)+1][2] = MFMA16(af1, bf[2], acc[2*(ip)+1][2]);         \
    acc[2*(ip)+1][3] = MFMA16(af1, bf[3], acc[2*(ip)+1][3]);         \
    __builtin_amdgcn_s_setprio(0);

#define BAR()   { __builtin_amdgcn_s_barrier(); asm volatile("" ::: "memory"); }
#define LGKM0() asm volatile("s_waitcnt lgkmcnt(0)" ::: "memory")

    for (int kt = 0; kt < NKT; ++kt) {
        const int d = kt & 1;
        const unsigned short* Ab = sm + d * 16384;
        const unsigned short* Bb = sm + 32768 + d * 16384;
        const bool s1 = (kt + 1 < NKT);
        const bool s2 = (kt + 2 < NKT);
        short8 af0, af1, bf[4];

        // ================= kh = 0 (phases 0-3) =================
        bf[0] = lds8(Bb + (wc * 4 + 0) * 512 + lane * 8);
        bf[1] = lds8(Bb + (wc * 4 + 1) * 512 + lane * 8);
        bf[2] = lds8(Bb + (wc * 4 + 2) * 512 + lane * 8);
        bf[3] = lds8(Bb + (wc * 4 + 3) * 512 + lane * 8);
        af0   = lds8(Ab + (wr * 8 + 0) * 512 + lane * 8);
        af1   = lds8(Ab + (wr * 8 + 1) * 512 + lane * 8);
        if (s1) STG_B(kt + 1, 1, 0);
        BAR(); LGKM0();
        DO_MFMA(0);
        BAR();

        af0 = lds8(Ab + (wr * 8 + 2) * 512 + lane * 8);
        af1 = lds8(Ab + (wr * 8 + 3) * 512 + lane * 8);
        if (s1) STG_B(kt + 1, 1, 1);
        BAR(); LGKM0();
        DO_MFMA(1);
        BAR();

        af0 = lds8(Ab + (wr * 8 + 4) * 512 + lane * 8);
        af1 = lds8(Ab + (wr * 8 + 5) * 512 + lane * 8);
        if (s1) STG_A(kt + 1, 1, 0);
        BAR(); LGKM0();
        DO_MFMA(2);
        BAR();

        af0 = lds8(Ab + (wr * 8 + 6) * 512 + lane * 8);
        af1 = lds8(Ab + (wr * 8 + 7) * 512 + lane * 8);
        if (s1) STG_A(kt + 1, 1, 1);
        BAR(); LGKM0();
        DO_MFMA(3);
        if (s1) asm volatile("s_waitcnt vmcnt(8)" ::: "memory");
        else    asm volatile("s_waitcnt vmcnt(0)" ::: "memory");
        BAR();

        // ================= kh = 1 (phases 4-7) =================
        bf[0] = lds8(Bb + 8192 + (wc * 4 + 0) * 512 + lane * 8);
        bf[1] = lds8(Bb + 8192 + (wc * 4 + 1) * 512 + lane * 8);
        bf[2] = lds8(Bb + 8192 + (wc * 4 + 2) * 512 + lane * 8);
        bf[3] = lds8(Bb + 8192 + (wc * 4 + 3) * 512 + lane * 8);
        af0   = lds8(Ab + 8192 + (wr * 8 + 0) * 512 + lane * 8);
        af1   = lds8(Ab + 8192 + (wr * 8 + 1) * 512 + lane * 8);
        if (s2) STG_B(kt + 2, 0, 0);
        BAR(); LGKM0();
        DO_MFMA(0);
        BAR();

        af0 = lds8(Ab + 8192 + (wr * 8 + 2) * 512 + lane * 8);
        af1 = lds8(Ab + 8192 + (wr * 8 + 3) * 512 + lane * 8);
        if (s2) STG_B(kt + 2, 0, 1);
        BAR(); LGKM0();
        DO_MFMA(1);
        BAR();

        af0 = lds8(Ab + 8192 + (wr * 8 + 4) * 512 + lane * 8);
        af1 = lds8(Ab + 8192 + (wr * 8 + 5) * 512 + lane * 8);
        if (s2) STG_A(kt + 2, 0, 0);
        BAR(); LGKM0();
        DO_MFMA(2);
        BAR();

        af0 = lds8(Ab + 8192 + (wr * 8 + 6) * 512 + lane * 8);
        af1 = lds8(Ab + 8192 + (wr * 8 + 7) * 512 + lane * 8);
        if (s2) STG_A(kt + 2, 0, 1);
        BAR(); LGKM0();
        DO_MFMA(3);
        if (s2)      asm volatile("s_waitcnt vmcnt(8)" ::: "memory");
        else if (s1) asm volatile("s_waitcnt vmcnt(4)" ::: "memory");
        else         asm volatile("s_waitcnt vmcnt(0)" ::: "memory");
        BAR();
    }
#undef STG_A
#undef STG_B
#undef DO_MFMA
#undef BAR
#undef LGKM0

    float2* tabf = reinterpret_cast<float2*>(sm);
    if (EPI == 0) {
        // RoPE table over dead LDS: 256 t x 32 d2 float2 = 64 KiB
        const int t0 = (bm & 15) * 256;
        for (int e = tid; e < 8192; e += 512) {
            int tl = e >> 5, d2 = e & 31;
            float f = (float)(t0 + tl) * exp2f(-(float)d2 * 0.41524101186092f);
            float sn, cs; __sincosf(f, &sn, &cs);
            tabf[tl * 32 + d2] = make_float2(cs, sn);
        }
        __syncthreads();
    }

#pragma unroll
    for (int i = 0; i < 8; ++i)
#pragma unroll
        for (int j = 0; j < 4; ++j)
#pragma unroll
            for (int r = 0; r < 4; ++r) {
                int row = bm * 256 + wr * 128 + i * 16 + quad * 4 + r;
                int col = bn * 256 + wc * 64 + j * 16 + l15;
                float v = acc[i][j][r];
                if (EPI == 0) {
                    float p = __shfl_xor(v, 1);
                    int t_ = row & 4095, b_ = row >> 12;
                    int hh = col >> 6, d = col & 63;
                    int tl = wr * 128 + i * 16 + quad * 4 + r;
                    float2 cspair = tabf[tl * 32 + (d >> 1)];
                    float o = (d & 1) ? (p * cspair.y + v * cspair.x)
                                      : (v * cspair.x - p * cspair.y);
                    o *= QSCALE;
                    float po = __shfl_xor(o, 1);
                    if (!(lane & 1)) {
                        unsigned int pk = (unsigned int)f2bf(o) |
                                          ((unsigned int)f2bf(po) << 16);
                        *reinterpret_cast<unsigned int*>(
                            Cb + ((size_t)((b_ * 32 + hh) * 4096 + t_)) * 64 + d) = pk;
                    }
                } else {
                    Cf[(size_t)row * 2048 + col] = v;
                }
            }
}

// ---------------- flash attention over 1024-key window ----------------
// Swapped-operand form (T12) + in-register P repack; 512-thread / 8-wave
// blocks covering 128 queries; K/V LDS tiles shared by 8 waves. L via MFMA
// ones-trick; T5 setprio around MFMA clusters. (Unchanged from R7.)
__global__ __launch_bounds__(512, 8)
void attn(const unsigned short* __restrict__ Q,
          const unsigned short* __restrict__ Kw,
          const unsigned short* __restrict__ Vt,
          unsigned short* __restrict__ O) {
    const int blk  = blockIdx.x;
    const int qblk = blk & 31;          // 32 blocks of 128 queries
    const int bh   = blk >> 5;
    const int h    = bh & 31;
    const int b    = bh >> 5;
    const int kvh  = h >> 2;

    const int tid  = threadIdx.x;
    const int lane = tid & 63;
    const int l15  = lane & 15;
    const int quad = lane >> 4;
    const int wid  = tid >> 6;          // 0..7
    const int qt0  = qblk * 128 + wid * 16;

    const unsigned short* Qp = Q  + ((size_t)bh * 4096 + qt0) * 64;
    const unsigned short* Kp = Kw + (size_t)(b * 8 + kvh) * 1024 * 64;
    const unsigned short* Vp = Vt + (size_t)(b * 8 + kvh) * 64 * 1024;

    // [buf][frag(8) * 512 + lane*8]; frag (c*2+half) for K, (j*2+shalf) for V
    __shared__ unsigned short Ks[2][4096];
    __shared__ unsigned short Vs[2][4096];

    short8 qa0 = lds8(&Qp[l15 * 64 + quad * 8]);
    short8 qa1 = lds8(&Qp[l15 * 64 + 32 + quad * 8]);

    short8 ones;                         // bf16 1.0 x8 (A-frag of all-ones)
#pragma unroll
    for (int i = 0; i < 8; ++i) ones[i] = (short)0x3F80;

    // staging: wave w stages K frag f=w and V frag f=w
    const unsigned short* gK = Kp + (size_t)((wid >> 1) * 16 + l15) * 64
                                  + (wid & 1) * 32 + quad * 8;
    const unsigned short* gV = Vp + (size_t)((wid >> 1) * 16 + l15) * 1024
                                  + (wid & 1) * 32 + quad * 8;
    unsigned short* sK0 = &Ks[0][wid * 512];
    unsigned short* sK1 = &Ks[1][wid * 512];
    unsigned short* sV0 = &Vs[0][wid * 512];
    unsigned short* sV1 = &Vs[1][wid * 512];

    const int ntiles = (qblk < 7 ? 2 * qblk + 2 : 16);      // block-uniform
    const int nkW    = (qt0 + 16 < 1024) ? qt0 + 16 : 1024; // per-wave keys
    const int ntW    = (nkW + 63) >> 6;                     // wave's tile count
    const bool diagW = (qt0 < 1024);

    // prefetch tile 0
    g2l16(gK, sK0);
    g2l16(gV, sV0);

    floatx4 o0 = {0,0,0,0}, o1 = {0,0,0,0}, o2 = {0,0,0,0}, o3 = {0,0,0,0};
    floatx4 La = {0,0,0,0};
    float m = -INFINITY;

    for (int it = 0; it < ntiles; ++it) {
        __syncthreads();                         // staging of tile `it` complete
        const int cur = it & 1;
        if (it + 1 < ntiles) {                   // prefetch next into other buffer
            g2l16(gK + (it + 1) * 4096, cur ? sK0 : sK1);
            g2l16(gV + (it + 1) * 64,   cur ? sV0 : sV1);
        }
        if (it >= ntW) continue;                 // wave done (barriers stay uniform)
        const int s0 = it << 6;
        const unsigned short* Kc = Ks[cur];
        const unsigned short* Vc = Vs[cur];

        // S^T = K·Q^T: lane holds S[key = s0 + c*16 + quad*4 + r][query = qt0 + l15]
        floatx4 sS[4];
        __builtin_amdgcn_s_setprio(1);
#pragma unroll
        for (int c = 0; c < 4; ++c) {
            floatx4 z = {0, 0, 0, 0};
            z = MFMA16(lds8(Kc + c * 1024 + lane * 8), qa0, z);
            z = MFMA16(lds8(Kc + c * 1024 + 512 + lane * 8), qa1, z);
            sS[c] = z;
        }
        __builtin_amdgcn_s_setprio(0);

        const bool last = (it == ntW - 1);
        bool skipHi = false;
        if (last && diagW) {                     // diagonal tile: causal mask
#pragma unroll
            for (int c = 0; c < 4; ++c)
#pragma unroll
                for (int r = 0; r < 4; ++r)
                    if (s0 + c * 16 + quad * 4 + r > qt0 + l15) sS[c][r] = -INFINITY;
            skipHi = (nkW - s0 <= 32);
        }

        // per-query tile max: max3 tree + quad reduce (keys live on quad bits)
        float t0 = fmaxf(fmaxf(sS[0][0], sS[0][1]), fmaxf(sS[0][2], sS[0][3]));
        float t1 = fmaxf(fmaxf(sS[1][0], sS[1][1]), fmaxf(sS[1][2], sS[1][3]));
        float t2 = fmaxf(fmaxf(sS[2][0], sS[2][1]), fmaxf(sS[2][2], sS[2][3]));
        float t3 = fmaxf(fmaxf(sS[3][0], sS[3][1]), fmaxf(sS[3][2], sS[3][3]));
        float mx = fmaxf(fmaxf(t0, t1), fmaxf(t2, t3));
        mx = fmaxf(mx, __shfl_xor(mx, 16));
        mx = fmaxf(mx, __shfl_xor(mx, 32));      // quad-uniform per query l15

        // defer-max (T13): only rescale when tile max exceeds m by > 8
        if (!__all(mx <= m + 8.0f)) {
            const float mn = fmaxf(m, mx);       // quad-uniform per query
            const float alpha = exp2f(m - mn);   // m=-inf first tile -> alpha=0
            m = mn;
            o0 *= alpha; o1 *= alpha; o2 *= alpha; o3 *= alpha;
            La *= alpha;
        }

        float p[4][4];
#pragma unroll
        for (int c = 0; c < 4; ++c)
#pragma unroll
            for (int r = 0; r < 4; ++r) p[c][r] = exp2f(sS[c][r] - m);

        // in-register P repack: keys 0-31 (chunks 0,1) -> pa_lo
        unsigned int a0 = cvtpk(p[0][0], p[0][1]);
        unsigned int a1 = cvtpk(p[0][2], p[0][3]);
        unsigned int a2 = cvtpk(p[1][0], p[1][1]);
        unsigned int a3 = cvtpk(p[1][2], p[1][3]);
        pl32swap(a0, a2); pl32swap(a1, a3);
        pl16swap(a0, a2); pl16swap(a1, a3);
        uintx4 tlo = {a0, a1, a2, a3};
        short8 pa_lo = __builtin_bit_cast(short8, tlo);

        // O^T += V^T · P^T ; L += ones · P^T (full 32-key sum per query)
        __builtin_amdgcn_s_setprio(1);
        o0 = MFMA16(lds8(Vc + 0 * 512 + lane * 8), pa_lo, o0);
        o1 = MFMA16(lds8(Vc + 2 * 512 + lane * 8), pa_lo, o1);
        o2 = MFMA16(lds8(Vc + 4 * 512 + lane * 8), pa_lo, o2);
        o3 = MFMA16(lds8(Vc + 6 * 512 + lane * 8), pa_lo, o3);
        La = MFMA16(ones, pa_lo, La);
        __builtin_amdgcn_s_setprio(0);
        if (!skipHi) {
            // keys 32-63 (chunks 2,3) -> pa_hi
            unsigned int b0 = cvtpk(p[2][0], p[2][1]);
            unsigned int b1 = cvtpk(p[2][2], p[2][3]);
            unsigned int b2 = cvtpk(p[3][0], p[3][1]);
            unsigned int b3 = cvtpk(p[3][2], p[3][3]);
            pl32swap(b0, b2); pl32swap(b1, b3);
            pl16swap(b0, b2); pl16swap(b1, b3);
            uintx4 thi = {b0, b1, b2, b3};
            short8 pa_hi = __builtin_bit_cast(short8, thi);
            __builtin_amdgcn_s_setprio(1);
            o0 = MFMA16(lds8(Vc + 1 * 512 + lane * 8), pa_hi, o0);
            o1 = MFMA16(lds8(Vc + 3 * 512 + lane * 8), pa_hi, o1);
            o2 = MFMA16(lds8(Vc + 5 * 512 + lane * 8), pa_hi, o2);
            o3 = MFMA16(lds8(Vc + 7 * 512 + lane * 8), pa_hi, o3);
            La = MFMA16(ones, pa_hi, La);
            __builtin_amdgcn_s_setprio(0);
        }
    }

    const float inv = 1.f / La[0];      // all 4 entries equal (full key sum)

    // O^T layout: lane holds O[q = qt0+l15][d = j*16 + quad*4 + r] -> 8B stores
    unsigned short* Op = O + (size_t)b * 4096 * 2048 + (size_t)(qt0 + l15) * 2048
                           + h * 64 + quad * 4;
    uintx2 w0, w1, w2, w3;
    w0.x = cvtpk(o0[0] * inv, o0[1] * inv); w0.y = cvtpk(o0[2] * inv, o0[3] * inv);
    w1.x = cvtpk(o1[0] * inv, o1[1] * inv); w1.y = cvtpk(o1[2] * inv, o1[3] * inv);
    w2.x = cvtpk(o2[0] * inv, o2[1] * inv); w2.y = cvtpk(o2[2] * inv, o2[3] * inv);
    w3.x = cvtpk(o3[0] * inv, o3[1] * inv); w3.y = cvtpk(o3[2] * inv, o3[3] * inv);
    *reinterpret_cast<uintx2*>(Op)      = w0;
    *reinterpret_cast<uintx2*>(Op + 16) = w1;
    *reinterpret_cast<uintx2*>(Op + 32) = w2;
    *reinterpret_cast<uintx2*>(Op + 48) = w3;
}

// ---------------- launch ----------------
extern "C" void kernel_launch(void* const* d_in, const int* in_sizes, int n_in,
                              void* d_out, int out_size, void* d_ws, size_t ws_size,
                              hipStream_t stream) {
    const float* x  = (const float*)d_in[0];
    const float* kc = (const float*)d_in[1];
    const float* vc = (const float*)d_in[2];
    const float* Wq = (const float*)d_in[3];
    const float* Wo = (const float*)d_in[4];
    float* out = (float*)d_out;

    char* ws = (char*)d_ws;
    unsigned short* Xb  = (unsigned short*)(ws);              // 33,554,432 B (reused as O)
    unsigned short* Qb  = (unsigned short*)(ws + 33554432);   // 33,554,432 B
    unsigned short* Wqb = (unsigned short*)(ws + 67108864);   //  8,388,608 B
    unsigned short* Wob = (unsigned short*)(ws + 75497472);   //  8,388,608 B
    unsigned short* Kwb = (unsigned short*)(ws + 83886080);   //  2,097,152 B
    unsigned short* Vtb = (unsigned short*)(ws + 85983232);   //  2,097,152 B

    cvt_bf16<<<16384, 256, 0, stream>>>(x,  Xb,  4194304);
    cvt_bf16<<<4096,  256, 0, stream>>>(Wq, Wqb, 1048576);
    cvt_bf16<<<4096,  256, 0, stream>>>(Wo, Wob, 1048576);
    prep_k<<<1024, 256, 0, stream>>>(kc, Kwb);
    prep_v<<<256, 256, 0, stream>>>(vc, Vtb);

    gemmk<0><<<256, 512, 0, stream>>>(Xb, Wqb, nullptr, Qb);   // Q + RoPE (pre-scaled)
    attn<<<2048, 512, 0, stream>>>(Qb, Kwb, Vtb, Xb);          // O -> Xb
    gemmk<1><<<256, 512, 0, stream>>>(Xb, Wob, out, nullptr);  // out proj
}